// Round 9
// baseline (2186.945 us; speedup 1.0000x reference)
//
#include <hip/hip_runtime.h>
#include <hip/hip_bf16.h>
#include <stdint.h>
#include <stdlib.h>
#include <math.h>

typedef __hip_bfloat16 bf16;
typedef unsigned short ushort;
typedef __attribute__((ext_vector_type(8))) short bhalf8;   // 8 bf16 (4 VGPRs)
typedef __attribute__((ext_vector_type(4))) float f32x4;    // MFMA C/D

// ---------------- problem constants ----------------
#define Bn 64
#define Sn 50
#define Tn 50
#define Hn 256

// output element offsets (flat concat)
#define OFF_CTX_OUT   0
#define OFF_CTX_HID   819200
#define OFF_RESP_OUT  835584
#define OFF_RESP_HID  2473984
#define OFF_SPK_EMB   2506752
#define OFF_SPK_MASK  3342336

// ---------------- workspace layout ----------------
#define WS_FLAG   0u          /* 4B dtype flag (1=bf16 inputs, 0=f32) */
#define WS_HU     256u        /* 3200*256 bf16 utterance final hidden */
#define WS_REG    1638912u    /* aliased region, 24,704,000 B */
// phase 1 (utterance encoder):
#define RG_UTTQ   0u          /* int8 [32000][768] = 24,576,000 */
#define RG_UTTSC  24576000u   /* f32 [32000] = 128,000 (dead after rec_utt) */
// phase 2 (after rec_utt; UQ/USC dead):
#define RG_RESPGI 0u          /* bf16 [6400][768] = 9,830,400 (live thru tail) */
#define RG_GIC    13107200u   /* bf16 [3200][768] = 4,915,200 (live thru tail) */
#define RG_TBL    22937600u   /* bf16 bits [64][51][256] = 1,671,168 (H2D after rec_utt) */
#define WS_END    26342912u

// ---------------- device helpers ----------------
__device__ __forceinline__ float b2f_bits(unsigned int b) {
    union { unsigned int u; float f; } c; c.u = b; return c.f;
}
__device__ __forceinline__ float bf2f(ushort v) { return b2f_bits(((unsigned int)v) << 16); }
__device__ __forceinline__ ushort f2bf(float f) {          // RNE f32 -> bf16 bits
    union { float f; unsigned int u; } c; c.f = f;
    return (ushort)((c.u + 0x7fffu + ((c.u >> 16) & 1u)) >> 16);
}
// async global->LDS copy, 16 B per active lane; LDS dest = row base + lane*16
__device__ __forceinline__ void gld_lds16(const void* g, void* l) {
    __builtin_amdgcn_global_load_lds(
        (const __attribute__((address_space(1))) void*)g,
        (__attribute__((address_space(3))) void*)l, 16, 0, 0);
}
// load 8 consecutive elements at index i as a bf16 MFMA fragment
template<bool BF>
__device__ __forceinline__ bhalf8 ldfrag(const void* __restrict__ p, size_t i) {
    if (BF) {
        return *(const bhalf8*)((const ushort*)p + i);
    } else {
        const float* q = (const float*)p + i;
        float4 a = *(const float4*)q;
        float4 b = *(const float4*)(q + 4);
        bhalf8 r;
        r[0] = (short)f2bf(a.x); r[1] = (short)f2bf(a.y);
        r[2] = (short)f2bf(a.z); r[3] = (short)f2bf(a.w);
        r[4] = (short)f2bf(b.x); r[5] = (short)f2bf(b.y);
        r[6] = (short)f2bf(b.z); r[7] = (short)f2bf(b.w);
        return r;
    }
}
template<bool BF>
__device__ __forceinline__ float ldw(const void* __restrict__ p, int i) {
    return BF ? bf2f(((const ushort*)p)[i]) : ((const float*)p)[i];
}
template<bool BF>
__device__ __forceinline__ void stout(void* __restrict__ out, size_t i, float v) {
    if (BF) ((ushort*)out)[i] = f2bf(v);
    else    ((float*)out)[i] = v;
}
__device__ __forceinline__ float fsigm(float x) {
    return __builtin_amdgcn_rcpf(1.f + __expf(-x));
}
__device__ __forceinline__ float ftanh(float x) {
    float e = __expf(-2.f * x);
    return (1.f - e) * __builtin_amdgcn_rcpf(1.f + e);
}

// ================= dtype sniffer =================
__global__ void sniff_kernel(const void* __restrict__ w, int* __restrict__ flag) {
    const unsigned int* p = (const unsigned int*)w;
    int tid = threadIdx.x;
    bool big = false;
    for (int i = tid; i < 512; i += 64) {
        float v = b2f_bits(p[i] << 16);
        if (!(fabsf(v) <= 1.0f)) big = true;   // catches NaN too
    }
    unsigned long long m = __ballot(big);
    if (tid == 0) *flag = (m == 0ull) ? 1 : 0;
}

// ===================================================================
// MFMA 16x16x32 bf16 layouts (m89/m120 verified):
//   A[m = lane&15][k = (lane>>4)*8 + j]
//   B[k = (lane>>4)*8 + j][n = lane&15]
//   D[row = (lane>>4)*4 + reg][col = lane&15]
// 512-thread blocks: 8 waves, wave w owns cols {g*256 + 32w + 16*ctl + c}.
// ===================================================================

// ---- utterance vocab gate table: Q[v][768] int8, SC[v] f32 ----
template<bool BF>
__device__ void vocab_utt_body(
    const void* __restrict__ emb_u, const void* __restrict__ uWih,
    const void* __restrict__ ubih,
    char* __restrict__ Q, float* __restrict__ SC,
    float* bhs, float (*rmx)[16])
{
    const int tid = threadIdx.x;
    const int w = tid >> 6, l = tid & 63, quad = l >> 4, c = l & 15;

    for (int i = tid; i < 768; i += 512) bhs[i] = ldw<BF>(ubih, i);

    bhalf8 wf[3][2][8];
    #pragma unroll
    for (int g = 0; g < 3; ++g)
        #pragma unroll
        for (int ctl = 0; ctl < 2; ++ctl) {
            const int gcol = g * 256 + 32 * w + 16 * ctl + c;
            #pragma unroll
            for (int tk = 0; tk < 8; ++tk)
                wf[g][ctl][tk] = ldfrag<BF>(uWih, (size_t)gcol * 256 + 32 * tk + 8 * quad);
        }
    __syncthreads();

    for (int vt = blockIdx.x; vt < 2000; vt += gridDim.x) {
        f32x4 acc[3][2];
        #pragma unroll
        for (int g = 0; g < 3; ++g)
            #pragma unroll
            for (int ctl = 0; ctl < 2; ++ctl) {
                float b = bhs[g * 256 + 32 * w + 16 * ctl + c];
                acc[g][ctl] = (f32x4){b, b, b, b};
            }
        #pragma unroll
        for (int tk = 0; tk < 8; ++tk) {
            bhalf8 a = ldfrag<BF>(emb_u, (size_t)(vt * 16 + c) * 256 + 32 * tk + 8 * quad);
            #pragma unroll
            for (int g = 0; g < 3; ++g)
                #pragma unroll
                for (int ctl = 0; ctl < 2; ++ctl)
                    acc[g][ctl] = __builtin_amdgcn_mfma_f32_16x16x32_bf16(
                        a, wf[g][ctl][tk], acc[g][ctl], 0, 0, 0);
        }

        float mx[4];
        #pragma unroll
        for (int r = 0; r < 4; ++r) {
            float v = 0.f;
            #pragma unroll
            for (int g = 0; g < 3; ++g)
                #pragma unroll
                for (int ctl = 0; ctl < 2; ++ctl)
                    v = fmaxf(v, fabsf(acc[g][ctl][r]));
            mx[r] = v;
        }
        #pragma unroll
        for (int off = 1; off < 16; off <<= 1)
            #pragma unroll
            for (int r = 0; r < 4; ++r)
                mx[r] = fmaxf(mx[r], __shfl_xor(mx[r], off));
        if (c == 0)
            #pragma unroll
            for (int r = 0; r < 4; ++r) rmx[w][4 * quad + r] = mx[r];
        __syncthreads();

        #pragma unroll
        for (int r = 0; r < 4; ++r) {
            const int m = 4 * quad + r;
            float s = fmaxf(fmaxf(fmaxf(rmx[0][m], rmx[1][m]), fmaxf(rmx[2][m], rmx[3][m])),
                            fmaxf(fmaxf(rmx[4][m], rmx[5][m]), fmaxf(rmx[6][m], rmx[7][m])));
            float scale = s * (1.f / 127.f);
            float inv   = (s > 0.f) ? (127.f / s) : 0.f;
            #pragma unroll
            for (int g = 0; g < 3; ++g)
                #pragma unroll
                for (int ctl = 0; ctl < 2; ++ctl) {
                    int qv = __float2int_rn(acc[g][ctl][r] * inv);
                    qv = max(-127, min(127, qv));
                    Q[(size_t)(vt * 16 + m) * 768 + g * 256 + 32 * w + 16 * ctl + c] = (char)qv;
                }
            if (w == 0 && c == 0) SC[vt * 16 + m] = scale;
        }
        __syncthreads();
    }
}

__global__ __launch_bounds__(512, 1) void vocab_utt_kernel(
    const void* emb_u, const void* uWih, const void* ubih,
    char* Q, float* SC, const int* flag)
{
    __shared__ float bhs[768];
    __shared__ float rmx[8][16];
    if (*flag) vocab_utt_body<true >(emb_u, uWih, ubih, Q, SC, bhs, rmx);
    else       vocab_utt_body<false>(emb_u, uWih, ubih, Q, SC, bhs, rmx);
}

// ---- utterance GRU recurrence: 200 blocks x 16 seqs (512 thr, dbuf, async prefetch) ----
template<bool BF>
__device__ void rec_utt_body(
    const int* __restrict__ ctx_tok,
    const char* __restrict__ Q, const float* __restrict__ SC,
    const void* __restrict__ uWhh, const void* __restrict__ ubhh,
    ushort* __restrict__ H_u,
    char (*gq)[16][784], float* gsc_all /*[Tn*16]*/, ushort (*hb)[16][264])
{
    const int n0 = blockIdx.x * 16;
    const int tid = threadIdx.x;
    const int w = tid >> 6, l = tid & 63, quad = l >> 4, c = l & 15;

    for (int i = tid; i < 16 * 264; i += 512) (&hb[0][0][0])[i] = 0;
    // all 800 per-token scales up-front
    for (int i = tid; i < Tn * 16; i += 512) {
        const int t = i >> 4, m = i & 15;
        gsc_all[i] = SC[ctx_tok[(n0 + m) * Tn + t]];
    }

    float breg[3][2];
    #pragma unroll
    for (int g = 0; g < 3; ++g)
        #pragma unroll
        for (int ctl = 0; ctl < 2; ++ctl)
            breg[g][ctl] = ldw<BF>(ubhh, g * 256 + 32 * w + 16 * ctl + c);

    bhalf8 wf[3][2][8];
    #pragma unroll
    for (int g = 0; g < 3; ++g)
        #pragma unroll
        for (int ctl = 0; ctl < 2; ++ctl) {
            const int gcol = g * 256 + 32 * w + 16 * ctl + c;
            #pragma unroll
            for (int tk = 0; tk < 8; ++tk)
                wf[g][ctl][tk] = ldfrag<BF>(uWhh, (size_t)gcol * 256 + 32 * tk + 8 * quad);
        }

    float st[2][4];
    #pragma unroll
    for (int ctl = 0; ctl < 2; ++ctl)
        #pragma unroll
        for (int r = 0; r < 4; ++r) st[ctl][r] = 0.f;

    // preload gi(0) into buffer 0: wave w copies rows {2w, 2w+1}, 768 B each
    #pragma unroll
    for (int k = 0; k < 2; ++k) {
        const int m = 2 * w + k;
        const int tok = ctx_tok[(n0 + m) * Tn + 0];
        if (l < 48)
            gld_lds16(Q + (size_t)tok * 768 + l * 16, &gq[0][m][0]);
    }
    __syncthreads();

    int p = 0;
    for (int t = 0; t < Tn; ++t) {
        // async prefetch of gi(t+1) into the other buffer (no registers held)
        if (t < Tn - 1) {
            #pragma unroll
            for (int k = 0; k < 2; ++k) {
                const int m = 2 * w + k;
                const int tok = ctx_tok[(n0 + m) * Tn + t + 1];
                if (l < 48)
                    gld_lds16(Q + (size_t)tok * 768 + l * 16, &gq[p ^ 1][m][0]);
            }
        }

        f32x4 acc[3][2];
        #pragma unroll
        for (int g = 0; g < 3; ++g)
            #pragma unroll
            for (int ctl = 0; ctl < 2; ++ctl) {
                float b = breg[g][ctl];
                acc[g][ctl] = (f32x4){b, b, b, b};
            }
        #pragma unroll
        for (int tk = 0; tk < 8; ++tk) {
            bhalf8 a = *(const bhalf8*)(&hb[p][c][32 * tk + 8 * quad]);
            #pragma unroll
            for (int g = 0; g < 3; ++g)
                #pragma unroll
                for (int ctl = 0; ctl < 2; ++ctl)
                    acc[g][ctl] = __builtin_amdgcn_mfma_f32_16x16x32_bf16(
                        a, wf[g][ctl][tk], acc[g][ctl], 0, 0, 0);
        }

        #pragma unroll
        for (int ctl = 0; ctl < 2; ++ctl) {
            const int u = 32 * w + 16 * ctl + c;
            #pragma unroll
            for (int r = 0; r < 4; ++r) {
                const int m = 4 * quad + r;
                const float s = gsc_all[t * 16 + m];
                float gr = s * (float)(signed char)gq[p][m][u];
                float gz = s * (float)(signed char)gq[p][m][256 + u];
                float gn = s * (float)(signed char)gq[p][m][512 + u];
                float rr = fsigm(gr + acc[0][ctl][r]);
                float zz = fsigm(gz + acc[1][ctl][r]);
                float nn = ftanh(gn + rr * acc[2][ctl][r]);
                float h  = (1.f - zz) * nn + zz * st[ctl][r];
                st[ctl][r] = h;
                hb[p ^ 1][m][u] = f2bf(h);
            }
        }
        __syncthreads();   // drains lds writes AND the async copies
        p ^= 1;
    }

    #pragma unroll
    for (int ctl = 0; ctl < 2; ++ctl)
        #pragma unroll
        for (int r = 0; r < 4; ++r)
            H_u[(size_t)(n0 + 4 * quad + r) * Hn + 32 * w + 16 * ctl + c] = f2bf(st[ctl][r]);
}

__global__ __launch_bounds__(512, 1) void rec_utt_kernel(
    const int* ctx_tok, const char* Q, const float* SC,
    const void* uWhh, const void* ubhh, ushort* H_u, const int* flag)
{
    __shared__ __align__(16) char   gq[2][16][784];
    __shared__ float  gsc_all[Tn * 16];
    __shared__ __align__(16) ushort hb[2][16][264];
    if (*flag) rec_utt_body<true >(ctx_tok, Q, SC, uWhh, ubhh, H_u, gq, gsc_all, hb);
    else       rec_utt_body<false>(ctx_tok, Q, SC, uWhh, ubhh, H_u, gq, gsc_all, hb);
}

// ---- response per-instance gates: RG[inst][768] bf16 (inst = n*50+t) ----
template<bool BF>
__device__ void respgi_body(
    int bid,
    const int* __restrict__ rsp_tok, const void* __restrict__ emb_r,
    const void* __restrict__ rWih, const void* __restrict__ rbih,
    ushort* __restrict__ RG, float* bhs)
{
    const int tid = threadIdx.x;
    const int w = tid >> 6, l = tid & 63, quad = l >> 4, c = l & 15;

    for (int i = tid; i < 768; i += 512) bhs[i] = ldw<BF>(rbih, i);

    bhalf8 wf[3][2][8];
    #pragma unroll
    for (int g = 0; g < 3; ++g)
        #pragma unroll
        for (int ctl = 0; ctl < 2; ++ctl) {
            const int gcol = g * 256 + 32 * w + 16 * ctl + c;
            #pragma unroll
            for (int tk = 0; tk < 8; ++tk)
                wf[g][ctl][tk] = ldfrag<BF>(rWih, (size_t)gcol * 256 + 32 * tk + 8 * quad);
        }
    __syncthreads();

    const int inst = bid * 16 + c;      // 6400 instances / 16 per block
    const int tok  = rsp_tok[inst];

    f32x4 acc[3][2];
    #pragma unroll
    for (int g = 0; g < 3; ++g)
        #pragma unroll
        for (int ctl = 0; ctl < 2; ++ctl) {
            float b = bhs[g * 256 + 32 * w + 16 * ctl + c];
            acc[g][ctl] = (f32x4){b, b, b, b};
        }
    #pragma unroll
    for (int tk = 0; tk < 8; ++tk) {
        bhalf8 a = ldfrag<BF>(emb_r, (size_t)tok * 256 + 32 * tk + 8 * quad);
        #pragma unroll
        for (int g = 0; g < 3; ++g)
            #pragma unroll
            for (int ctl = 0; ctl < 2; ++ctl)
                acc[g][ctl] = __builtin_amdgcn_mfma_f32_16x16x32_bf16(
                    a, wf[g][ctl][tk], acc[g][ctl], 0, 0, 0);
    }
    #pragma unroll
    for (int g = 0; g < 3; ++g)
        #pragma unroll
        for (int ctl = 0; ctl < 2; ++ctl)
            #pragma unroll
            for (int r = 0; r < 4; ++r)
                RG[(size_t)(bid * 16 + 4 * quad + r) * 768
                   + g * 256 + 32 * w + 16 * ctl + c] = f2bf(acc[g][ctl][r]);
}

// ============ ctx input gates (MFMA, K=512 in two passes): 200 blocks x 16 rows ============
template<bool BF>
__device__ void gi_ctx_body(
    int bid,
    const ushort* __restrict__ H_u, const ushort* __restrict__ tblbf,
    const int* __restrict__ spk_agents,
    const void* __restrict__ Wih, const void* __restrict__ bih,
    ushort* __restrict__ GIc, float* bhs)
{
    const int tid = threadIdx.x;
    const int w = tid >> 6, l = tid & 63, quad = l >> 4, c = l & 15;

    for (int i = tid; i < 768; i += 512) bhs[i] = ldw<BF>(bih, i);
    __syncthreads();

    // A row for lane c: m = m0+c (m = s*64+b)
    const int m0 = bid * 16;
    const int m  = m0 + c, s = m >> 6, b = m & 63;
    const int a  = spk_agents[b * Sn + s];
    const ushort* arow0 = H_u   + (size_t)(b * Sn + s) * Hn;   // k in [0,256)
    const ushort* arow1 = tblbf + (size_t)(b * 51 + a) * Hn;   // k in [256,512)

    f32x4 acc[3][2];
    #pragma unroll
    for (int g = 0; g < 3; ++g)
        #pragma unroll
        for (int ctl = 0; ctl < 2; ++ctl) {
            float bb = bhs[g * 256 + 32 * w + 16 * ctl + c];
            acc[g][ctl] = (f32x4){bb, bb, bb, bb};
        }

    for (int half = 0; half < 2; ++half) {
        const ushort* ar = half ? arow1 : arow0;
        bhalf8 af[8];
        #pragma unroll
        for (int tk = 0; tk < 8; ++tk)
            af[tk] = *(const bhalf8*)(ar + 32 * tk + 8 * quad);
        #pragma unroll
        for (int g = 0; g < 3; ++g) {
            bhalf8 wfl[2][8];
            #pragma unroll
            for (int ctl = 0; ctl < 2; ++ctl) {
                const int gcol = g * 256 + 32 * w + 16 * ctl + c;
                #pragma unroll
                for (int tk = 0; tk < 8; ++tk)
                    wfl[ctl][tk] = ldfrag<BF>(Wih,
                        (size_t)gcol * 512 + half * 256 + 32 * tk + 8 * quad);
            }
            #pragma unroll
            for (int tk = 0; tk < 8; ++tk)
                #pragma unroll
                for (int ctl = 0; ctl < 2; ++ctl)
                    acc[g][ctl] = __builtin_amdgcn_mfma_f32_16x16x32_bf16(
                        af[tk], wfl[ctl][tk], acc[g][ctl], 0, 0, 0);
        }
    }

    #pragma unroll
    for (int g = 0; g < 3; ++g)
        #pragma unroll
        for (int ctl = 0; ctl < 2; ++ctl)
            #pragma unroll
            for (int r = 0; r < 4; ++r)
                GIc[(size_t)(m0 + 4 * quad + r) * 768
                    + g * 256 + 32 * w + 16 * ctl + c] = f2bf(acc[g][ctl][r]);
}

// ============ fused gate kernel: respgi (blocks 0..399) ∪ gi_ctx (400..599) ============
__global__ __launch_bounds__(512, 1) void gates2_kernel(
    const int* rsp_tok, const void* emb_r, const void* rWih, const void* rbih,
    ushort* RG,
    const ushort* H_u, const ushort* tblbf, const int* spk_agents,
    const void* cWih, const void* cbih, ushort* GIc, const int* flag)
{
    __shared__ float bhs[768];
    if (blockIdx.x < 400) {
        if (*flag) respgi_body<true >(blockIdx.x, rsp_tok, emb_r, rWih, rbih, RG, bhs);
        else       respgi_body<false>(blockIdx.x, rsp_tok, emb_r, rWih, rbih, RG, bhs);
    } else {
        const int bid = blockIdx.x - 400;
        if (*flag) gi_ctx_body<true >(bid, H_u, tblbf, spk_agents, cWih, cbih, GIc, bhs);
        else       gi_ctx_body<false>(bid, H_u, tblbf, spk_agents, cWih, cbih, GIc, bhs);
    }
}

// ---- response GRU recurrence body: blocks 16..23 of tail (512 thr, dbuf) ----
template<bool BF>
__device__ void rec_resp_body(
    int bid,
    const ushort* __restrict__ RG,
    const void* __restrict__ rWhh, const void* __restrict__ rbhh,
    void* __restrict__ outp, char* smem)
{
    ushort (*gx)[16][776] = (ushort(*)[16][776])(smem);            // 49,664 B
    ushort (*hb)[16][264] = (ushort(*)[16][264])(smem + 49664);    // 16,896 B

    const int n0 = bid * 16;
    const int tid = threadIdx.x;
    const int w = tid >> 6, l = tid & 63, quad = l >> 4, c = l & 15;

    for (int i = tid; i < 16 * 264; i += 512) (&hb[0][0][0])[i] = 0;

    float breg[3][2];
    #pragma unroll
    for (int g = 0; g < 3; ++g)
        #pragma unroll
        for (int ctl = 0; ctl < 2; ++ctl)
            breg[g][ctl] = ldw<BF>(rbhh, g * 256 + 32 * w + 16 * ctl + c);

    bhalf8 wf[3][2][8];
    #pragma unroll
    for (int g = 0; g < 3; ++g)
        #pragma unroll
        for (int ctl = 0; ctl < 2; ++ctl) {
            const int gcol = g * 256 + 32 * w + 16 * ctl + c;
            #pragma unroll
            for (int tk = 0; tk < 8; ++tk)
                wf[g][ctl][tk] = ldfrag<BF>(rWhh, (size_t)gcol * 256 + 32 * tk + 8 * quad);
        }

    float st[2][4];
    #pragma unroll
    for (int ctl = 0; ctl < 2; ++ctl)
        #pragma unroll
        for (int r = 0; r < 4; ++r) st[ctl][r] = 0.f;

    // preload gi(0): wave w copies rows {2w, 2w+1}, 1536 B each (2 chunks)
    #pragma unroll
    for (int k = 0; k < 2; ++k) {
        const int m = 2 * w + k;
        const ushort* src = RG + (size_t)((n0 + m) * Tn + 0) * 768;
        if (l < 48) {
            gld_lds16(src + l * 8,       &gx[0][m][0]);
            gld_lds16(src + 384 + l * 8, &gx[0][m][384]);
        }
    }
    __syncthreads();

    int p = 0;
    for (int t = 0; t < Tn; ++t) {
        // async prefetch of gi(t+1)
        if (t < Tn - 1) {
            #pragma unroll
            for (int k = 0; k < 2; ++k) {
                const int m = 2 * w + k;
                const ushort* src = RG + (size_t)((n0 + m) * Tn + t + 1) * 768;
                if (l < 48) {
                    gld_lds16(src + l * 8,       &gx[p ^ 1][m][0]);
                    gld_lds16(src + 384 + l * 8, &gx[p ^ 1][m][384]);
                }
            }
        }
        // deferred store of h(t-1)
        if (t > 0) {
            #pragma unroll
            for (int ctl = 0; ctl < 2; ++ctl) {
                const int u = 32 * w + 16 * ctl + c;
                #pragma unroll
                for (int r = 0; r < 4; ++r) {
                    const int n = n0 + 4 * quad + r, bb = n >> 1, ri = n & 1;
                    stout<BF>(outp, OFF_RESP_OUT
                              + (size_t)((ri * Tn + (t - 1)) * Bn + bb) * Hn + u,
                              st[ctl][r]);
                }
            }
        }

        f32x4 acc[3][2];
        #pragma unroll
        for (int g = 0; g < 3; ++g)
            #pragma unroll
            for (int ctl = 0; ctl < 2; ++ctl) {
                float b = breg[g][ctl];
                acc[g][ctl] = (f32x4){b, b, b, b};
            }
        #pragma unroll
        for (int tk = 0; tk < 8; ++tk) {
            bhalf8 a = *(const bhalf8*)(&hb[p][c][32 * tk + 8 * quad]);
            #pragma unroll
            for (int g = 0; g < 3; ++g)
                #pragma unroll
                for (int ctl = 0; ctl < 2; ++ctl)
                    acc[g][ctl] = __builtin_amdgcn_mfma_f32_16x16x32_bf16(
                        a, wf[g][ctl][tk], acc[g][ctl], 0, 0, 0);
        }

        #pragma unroll
        for (int ctl = 0; ctl < 2; ++ctl) {
            const int u = 32 * w + 16 * ctl + c;
            #pragma unroll
            for (int r = 0; r < 4; ++r) {
                const int m = 4 * quad + r;
                float gr = bf2f(gx[p][m][u]);
                float gz = bf2f(gx[p][m][256 + u]);
                float gn = bf2f(gx[p][m][512 + u]);
                float rr = fsigm(gr + acc[0][ctl][r]);
                float zz = fsigm(gz + acc[1][ctl][r]);
                float nn = ftanh(gn + rr * acc[2][ctl][r]);
                float h  = (1.f - zz) * nn + zz * st[ctl][r];
                st[ctl][r] = h;
                hb[p ^ 1][m][u] = f2bf(h);
            }
        }
        __syncthreads();
        p ^= 1;
    }

    // final stores: h(49) -> resp_out[t=49] and resp_hid
    #pragma unroll
    for (int ctl = 0; ctl < 2; ++ctl) {
        const int u = 32 * w + 16 * ctl + c;
        #pragma unroll
        for (int r = 0; r < 4; ++r) {
            const int n = n0 + 4 * quad + r, bb = n >> 1, ri = n & 1;
            stout<BF>(outp, OFF_RESP_OUT
                      + (size_t)((ri * Tn + (Tn - 1)) * Bn + bb) * Hn + u, st[ctl][r]);
            stout<BF>(outp, OFF_RESP_HID + (size_t)(ri * Bn + bb) * Hn + u, st[ctl][r]);
        }
    }
}

// ============ mega body: fused ctx GRU + spk gates + spk GRU, 4 batches/block ============
// Per step t: (1) ctx hidden GEMM + gate update (h_ctx(t)), (2) spk-gate GEMM
// gi_s = h_ctx(t) @ sWih (result stays in the SAME lane that consumes it),
// (3) spk hidden GEMM on gathered S row, (4) spk state update.  Weight
// fragments are streamed from global each use (same 6 KB/wave every step ->
// L1-hot); only A-frags + accumulators live in registers (no spill).
#define SSTR 264   /* LDS row stride for S */
template<bool BF>
__device__ void mega_body(
    int bid,
    const ushort* __restrict__ GIc,
    const void* __restrict__ cWhh, const void* __restrict__ cbhh,
    const void* __restrict__ sWih, const void* __restrict__ sbih,
    const void* __restrict__ sWhh, const void* __restrict__ sbhh,
    const int* __restrict__ spk_agents,
    void* __restrict__ outp, char* smem)
{
    ushort* S             = (ushort*)smem;                          // 107,712 B
    ushort (*hc)[16][264] = (ushort(*)[16][264])(smem + 107712);    // 16,896 B
    ushort (*gic)[4][776] = (ushort(*)[4][776])(smem + 124608);     // 12,416 B
    int*    pres          = (int*)(smem + 137024);                  // 816 B
    float*  cbh           = (float*)(smem + 137840);                // 3×768 f32
    float*  sbi           = cbh + 768;
    float*  sbh           = sbi + 768;

    const int b0 = bid * 4;
    const int tid = threadIdx.x;
    const int w = tid >> 6, l = tid & 63, quad = l >> 4, c = l & 15;

    for (int i = tid; i < 4 * 51 * SSTR; i += 512) S[i] = 0;
    for (int i = tid; i < 2 * 16 * 264; i += 512) (&hc[0][0][0])[i] = 0;
    for (int i = tid; i < 4 * 51; i += 512) pres[i] = 0;
    for (int i = tid; i < 768; i += 512) {
        cbh[i] = ldw<BF>(cbhh, i);
        sbi[i] = ldw<BF>(sbih, i);
        sbh[i] = ldw<BF>(sbhh, i);
    }

    float st[2][4];   // ctx hidden state (meaningful in quad-0 lanes)
    #pragma unroll
    for (int ctl = 0; ctl < 2; ++ctl)
        #pragma unroll
        for (int r = 0; r < 4; ++r) st[ctl][r] = 0.f;

    // preload gic[0]: wave w -> row w>>1, chunk w&1 (4 rows x 1536 B)
    {
        const int row = w >> 1, ch = w & 1;
        const ushort* src = GIc + (size_t)(0 * Bn + b0 + row) * 768 + ch * 384;
        if (l < 48) gld_lds16(src + l * 8, &gic[0][row][ch * 384]);
    }
    __syncthreads();

    int p = 0;
    for (int t = 0; t < Sn; ++t) {
        // async prefetch of gic(t+1)
        if (t < Sn - 1) {
            const int row = w >> 1, ch = w & 1;
            const ushort* src = GIc + (size_t)((t + 1) * Bn + b0 + row) * 768 + ch * 384;
            if (l < 48) gld_lds16(src + l * 8, &gic[p ^ 1][row][ch * 384]);
        }

        // ---- phase 1: ctx hidden GEMM (A rows 0-3 live, rest zero) ----
        bhalf8 areg[8];
        #pragma unroll
        for (int tk = 0; tk < 8; ++tk)
            areg[tk] = *(const bhalf8*)(&hc[p][c][32 * tk + 8 * quad]);
        f32x4 accc[3][2];
        #pragma unroll
        for (int g = 0; g < 3; ++g)
            #pragma unroll
            for (int ctl = 0; ctl < 2; ++ctl) {
                float b = cbh[g * 256 + 32 * w + 16 * ctl + c];
                accc[g][ctl] = (f32x4){b, b, b, b};
            }
        #pragma unroll
        for (int g = 0; g < 3; ++g)
            #pragma unroll
            for (int ctl = 0; ctl < 2; ++ctl) {
                const int gcol = g * 256 + 32 * w + 16 * ctl + c;
                bhalf8 wt[8];
                #pragma unroll
                for (int tk = 0; tk < 8; ++tk)
                    wt[tk] = ldfrag<BF>(cWhh, (size_t)gcol * 256 + 32 * tk + 8 * quad);
                #pragma unroll
                for (int tk = 0; tk < 8; ++tk)
                    accc[g][ctl] = __builtin_amdgcn_mfma_f32_16x16x32_bf16(
                        areg[tk], wt[tk], accc[g][ctl], 0, 0, 0);
            }
        // ctx gate update (batches = D rows 0-3 -> quad 0)
        if (quad == 0) {
            #pragma unroll
            for (int ctl = 0; ctl < 2; ++ctl) {
                const int u = 32 * w + 16 * ctl + c;
                #pragma unroll
                for (int r = 0; r < 4; ++r) {
                    float gr = bf2f(gic[p][r][u]);
                    float gz = bf2f(gic[p][r][256 + u]);
                    float gn = bf2f(gic[p][r][512 + u]);
                    float rr = fsigm(gr + accc[0][ctl][r]);
                    float zz = fsigm(gz + accc[1][ctl][r]);
                    float nn = ftanh(gn + rr * accc[2][ctl][r]);
                    float h  = (1.f - zz) * nn + zz * st[ctl][r];
                    st[ctl][r] = h;
                    hc[p ^ 1][r][u] = f2bf(h);
                    const size_t gri = (size_t)(t * Bn + b0 + r);
                    stout<BF>(outp, OFF_CTX_OUT + gri * Hn + u, h);
                    if (t == Sn - 1)
                        stout<BF>(outp, OFF_CTX_HID + (size_t)(b0 + r) * Hn + u, h);
                }
            }
        }
        __syncthreads();   // hc[p^1] ready; gic prefetch drained

        // ---- phase 2: spk gate GEMM  gi_s = h_ctx(t) @ sWih + sbih ----
        #pragma unroll
        for (int tk = 0; tk < 8; ++tk)
            areg[tk] = *(const bhalf8*)(&hc[p ^ 1][c][32 * tk + 8 * quad]);
        f32x4 accs[3][2];
        #pragma unroll
        for (int g = 0; g < 3; ++g)
            #pragma unroll
            for (int ctl = 0; ctl < 2; ++ctl) {
                float b = sbi[g * 256 + 32 * w + 16 * ctl + c];
                accs[g][ctl] = (f32x4){b, b, b, b};
            }
        #pragma unroll
        for (int g = 0; g < 3; ++g)
            #pragma unroll
            for (int ctl = 0; ctl < 2; ++ctl) {
                const int gcol = g * 256 + 32 * w + 16 * ctl + c;
                bhalf8 wt[8];
                #pragma unroll
                for (int tk = 0; tk < 8; ++tk)
                    wt[tk] = ldfrag<BF>(sWih, (size_t)gcol * 256 + 32 * tk + 8 * quad);
                #pragma unroll
                for (int tk = 0; tk < 8; ++tk)
                    accs[g][ctl] = __builtin_amdgcn_mfma_f32_16x16x32_bf16(
                        areg[tk], wt[tk], accs[g][ctl], 0, 0, 0);
            }

        // ---- phase 3: spk hidden GEMM on gathered S rows ----
        const int va = (c < 4) ? spk_agents[(b0 + c) * Sn + t] : 0;
        const int mb = (c < 4) ? c : 0;
        const ushort* srow = &S[(mb * 51 + va) * SSTR];
        #pragma unroll
        for (int tk = 0; tk < 8; ++tk)
            areg[tk] = *(const bhalf8*)(srow + 32 * tk + 8 * quad);
        f32x4 acch[3][2];
        #pragma unroll
        for (int g = 0; g < 3; ++g)
            #pragma unroll
            for (int ctl = 0; ctl < 2; ++ctl) {
                float b = sbh[g * 256 + 32 * w + 16 * ctl + c];
                acch[g][ctl] = (f32x4){b, b, b, b};
            }
        #pragma unroll
        for (int g = 0; g < 3; ++g)
            #pragma unroll
            for (int ctl = 0; ctl < 2; ++ctl) {
                const int gcol = g * 256 + 32 * w + 16 * ctl + c;
                bhalf8 wt[8];
                #pragma unroll
                for (int tk = 0; tk < 8; ++tk)
                    wt[tk] = ldfrag<BF>(sWhh, (size_t)gcol * 256 + 32 * tk + 8 * quad);
                #pragma unroll
                for (int tk = 0; tk < 8; ++tk)
                    acch[g][ctl] = __builtin_amdgcn_mfma_f32_16x16x32_bf16(
                        areg[tk], wt[tk], acch[g][ctl], 0, 0, 0);
            }
        __syncthreads();   // all S reads of step t complete

        // ---- phase 4: spk state update (quad 0; gi_s already in-lane) ----
        if (quad == 0) {
            int vv[4];
            #pragma unroll
            for (int r = 0; r < 4; ++r) vv[r] = spk_agents[(b0 + r) * Sn + t];
            #pragma unroll
            for (int ctl = 0; ctl < 2; ++ctl) {
                const int u = 32 * w + 16 * ctl + c;
                #pragma unroll
                for (int r = 0; r < 4; ++r) {
                    ushort* sp = &S[(r * 51 + vv[r]) * SSTR + u];
                    float hprev = bf2f(*sp);
                    float rr = fsigm(accs[0][ctl][r] + acch[0][ctl][r]);
                    float zz = fsigm(accs[1][ctl][r] + acch[1][ctl][r]);
                    float nn = ftanh(accs[2][ctl][r] + rr * acch[2][ctl][r]);
                    float h  = (1.f - zz) * nn + zz * hprev;
                    *sp = f2bf(h);
                }
            }
        }
        if (tid < 4) pres[tid * 51 + spk_agents[(b0 + tid) * Sn + t]] = 1;
        __syncthreads();   // S writes visible before next step's reads
        p ^= 1;
    }

    // final outputs: spk_emb (absent rows stay zero) + mask
    for (int idx = tid; idx < 4 * 51 * 256; idx += 512) {
        const int mb2 = idx / (51 * 256);
        const int rem = idx - mb2 * (51 * 256);
        const int v = rem >> 8, u = rem & 255;
        float val = bf2f(S[(mb2 * 51 + v) * SSTR + u]);
        stout<BF>(outp, OFF_SPK_EMB + (size_t)((b0 + mb2) * 51 + v) * Hn + u, val);
    }
    for (int idx = tid; idx < 4 * 51; idx += 512) {
        const int mb2 = idx / 51, v = idx - mb2 * 51;
        stout<BF>(outp, OFF_SPK_MASK + (size_t)((b0 + mb2) * 51 + v),
                  (pres[mb2 * 51 + v] && v > 0) ? 1.f : 0.f);
    }
}

// ============ tail kernel: mega ctx+spk (blocks 0..15) ∪ rec_resp (16..23) ============
__global__ __launch_bounds__(512, 1) void tail_kernel(
    const ushort* GIc, const void* cWhh, const void* cbhh,
    const void* sWih, const void* sbih, const void* sWhh, const void* sbhh,
    const int* spk_agents,
    const ushort* RG, const void* rWhh, const void* rbhh,
    void* outp, const int* flag)
{
    __shared__ __align__(16) char smem[147056];
    if (blockIdx.x < 16) {
        if (*flag) mega_body<true >(blockIdx.x, GIc, cWhh, cbhh, sWih, sbih,
                                    sWhh, sbhh, spk_agents, outp, smem);
        else       mega_body<false>(blockIdx.x, GIc, cWhh, cbhh, sWih, sbih,
                                    sWhh, sbhh, spk_agents, outp, smem);
    } else {
        const int bid = blockIdx.x - 16;
        if (*flag) rec_resp_body<true >(bid, RG, rWhh, rbhh, outp, smem);
        else       rec_resp_body<false>(bid, RG, rWhh, rbhh, outp, smem);
    }
}

// ================= host-side MT19937 (numpy legacy RandomState, seed 1) =================
namespace {
inline uint16_t host_f2bf(float f) {
    union { float f; uint32_t u; } c; c.f = f;
    return (uint16_t)((c.u + 0x7fffu + ((c.u >> 16) & 1u)) >> 16);
}
struct MT19937 {
    uint32_t mt[624]; int mti;
    void seed(uint32_t s) {
        mt[0] = s;
        for (int i = 1; i < 624; ++i)
            mt[i] = 1812433253u * (mt[i - 1] ^ (mt[i - 1] >> 30)) + (uint32_t)i;
        mti = 624;
    }
    uint32_t next() {
        if (mti >= 624) {
            for (int i = 0; i < 624; ++i) {
                uint32_t y = (mt[i] & 0x80000000u) | (mt[(i + 1) % 624] & 0x7fffffffu);
                mt[i] = mt[(i + 397) % 624] ^ (y >> 1) ^ ((y & 1u) ? 0x9908b0dfu : 0u);
            }
            mti = 0;
        }
        uint32_t y = mt[mti++];
        y ^= y >> 11; y ^= (y << 7) & 0x9d2c5680u; y ^= (y << 15) & 0xefc60000u; y ^= y >> 18;
        return y;
    }
    double rd() {
        uint32_t a = next() >> 5, b = next() >> 6;
        return (a * 67108864.0 + b) / 9007199254740992.0;
    }
};

uint16_t* get_host_tables() {      // bf16 bits (feeds MFMA A-fragments)
    static uint16_t* p = [] {
        void* q = nullptr;
        if (hipHostMalloc(&q, 835584 * sizeof(uint16_t), hipHostMallocDefault) != hipSuccess)
            q = malloc(835584 * sizeof(uint16_t));
        uint16_t* h = (uint16_t*)q;
        MT19937 g; g.seed(1u);
        for (int i = 0; i < 835584; ++i)
            h[i] = host_f2bf((float)g.rd());
        return h;
    }();
    return p;
}
} // namespace

// ================= launch =================
extern "C" void kernel_launch(void* const* d_in, const int* in_sizes, int n_in,
                              void* d_out, int out_size, void* d_ws, size_t ws_size,
                              hipStream_t stream)
{
    const int* ctx_tok    = (const int*)d_in[0];
    const int* rsp_tok    = (const int*)d_in[1];
    const int* spk_agents = (const int*)d_in[2];
    const void* emb_u = d_in[3];
    const void* emb_r = d_in[4];
    const void* uWih = d_in[5],  *uWhh = d_in[6],  *ubih = d_in[7],  *ubhh = d_in[8];
    const void* cWih = d_in[9],  *cWhh = d_in[10], *cbih = d_in[11], *cbhh = d_in[12];
    const void* rWih = d_in[13], *rWhh = d_in[14], *rbih = d_in[15], *rbhh = d_in[16];
    const void* sWih = d_in[17], *sWhh = d_in[18], *sbih = d_in[19], *sbhh = d_in[20];
    (void)in_sizes; (void)n_in; (void)out_size; (void)ws_size;

    char* ws  = (char*)d_ws;
    char* reg = ws + WS_REG;
    int*      flag = (int*)(ws + WS_FLAG);
    ushort*   H_u  = (ushort*)(ws + WS_HU);
    char*     UQ   = (char*)(reg + RG_UTTQ);
    float*    USC  = (float*)(reg + RG_UTTSC);
    ushort*   RG   = (ushort*)(reg + RG_RESPGI);
    ushort*   GIc  = (ushort*)(reg + RG_GIC);
    ushort*   tbl  = (ushort*)(reg + RG_TBL);
    void*     out  = d_out;

    sniff_kernel<<<1, 64, 0, stream>>>(uWih, flag);

    // utterance encoder (MFMA; dtype-dispatched on flag)
    vocab_utt_kernel<<<250, 512, 0, stream>>>(emb_u, uWih, ubih, UQ, USC, flag);
    rec_utt_kernel<<<200, 512, 0, stream>>>(ctx_tok, UQ, USC, uWhh, ubhh, H_u, flag);

    // agent tables H2D (bf16 bits) — after rec_utt so it may alias the dead UQ tail
    hipMemcpyAsync(tbl, get_host_tables(), 835584 * sizeof(uint16_t),
                   hipMemcpyHostToDevice, stream);

    // fused gate kernel: respgi (400 blk) ∥ gi_ctx (200 blk)
    gates2_kernel<<<600, 512, 0, stream>>>(rsp_tok, emb_r, rWih, rbih, RG,
                                           H_u, tbl, spk_agents, cWih, cbih, GIc, flag);

    // fused tail: [ctx GRU + spk gates + spk GRU] (16 blk) ∥ rec_resp (8 blk)
    tail_kernel<<<24, 512, 0, stream>>>(GIc, cWhh, cbhh, sWih, sbih, sWhh, sbhh,
                                        spk_agents, RG, rWhh, rbhh, out, flag);
}

// Round 10
// 1157.857 us; speedup vs baseline: 1.8888x; 1.8888x over previous
//
#include <hip/hip_runtime.h>
#include <hip/hip_bf16.h>
#include <stdint.h>
#include <stdlib.h>
#include <math.h>

typedef __hip_bfloat16 bf16;
typedef unsigned short ushort;
typedef __attribute__((ext_vector_type(8))) short bhalf8;   // 8 bf16 (4 VGPRs)
typedef __attribute__((ext_vector_type(4))) float f32x4;    // MFMA C/D

// ---------------- problem constants ----------------
#define Bn 64
#define Sn 50
#define Tn 50
#define Hn 256

// output element offsets (flat concat)
#define OFF_CTX_OUT   0
#define OFF_CTX_HID   819200
#define OFF_RESP_OUT  835584
#define OFF_RESP_HID  2473984
#define OFF_SPK_EMB   2506752
#define OFF_SPK_MASK  3342336

// ---------------- workspace layout (within proven 27.9 MB envelope) ----
#define WS_FLAG   0u          /* 4B dtype flag (1=bf16 inputs, 0=f32) */
#define WS_HU     256u        /* 3200*256 bf16 utterance final hidden */
#define WS_REG    1638912u    /* aliased region, 24,704,000 B */
// phase 1 (utterance encoder):
#define RG_UTTQ   0u          /* int8 [32000][768] = 24,576,000 */
#define RG_UTTSC  24576000u   /* f32 [32000] = 128,000 (dead after rec_utt) */
// phase 2 (after rec_utt; UQ/USC dead):
#define RG_RESPGI 0u          /* bf16 [6400][768] = 9,830,400 (live thru rec2) */
#define RG_CO     9830400u    /* f32 [3200][256] = 3,276,800 */
#define RG_GIC    13107200u   /* bf16 [3200][768] = 4,915,200 */
#define RG_GIS    18022400u   /* bf16 [3200][768] = 4,915,200 */
#define RG_TBL    22937600u   /* bf16 bits [64][51][256] = 1,671,168 (H2D after rec_utt) */
// speaker chain decomposition tables (after old WS_END; still < 27.9 MB):
#define WS_EV     26342912u   /* int [64*51][50] = 652,800 */
#define WS_CNT    26995712u   /* int [64*51] = 13,056 */
#define WS_END    27008768u

// ---------------- device helpers ----------------
__device__ __forceinline__ float b2f_bits(unsigned int b) {
    union { unsigned int u; float f; } c; c.u = b; return c.f;
}
__device__ __forceinline__ float bf2f(ushort v) { return b2f_bits(((unsigned int)v) << 16); }
__device__ __forceinline__ ushort f2bf(float f) {          // RNE f32 -> bf16 bits
    union { float f; unsigned int u; } c; c.f = f;
    return (ushort)((c.u + 0x7fffu + ((c.u >> 16) & 1u)) >> 16);
}
// async global->LDS copy, 16 B per active lane; LDS dest = row base + lane*16
__device__ __forceinline__ void gld_lds16(const void* g, void* l) {
    __builtin_amdgcn_global_load_lds(
        (const __attribute__((address_space(1))) void*)g,
        (__attribute__((address_space(3))) void*)l, 16, 0, 0);
}
// load 8 consecutive elements at index i as a bf16 MFMA fragment
template<bool BF>
__device__ __forceinline__ bhalf8 ldfrag(const void* __restrict__ p, size_t i) {
    if (BF) {
        return *(const bhalf8*)((const ushort*)p + i);
    } else {
        const float* q = (const float*)p + i;
        float4 a = *(const float4*)q;
        float4 b = *(const float4*)(q + 4);
        bhalf8 r;
        r[0] = (short)f2bf(a.x); r[1] = (short)f2bf(a.y);
        r[2] = (short)f2bf(a.z); r[3] = (short)f2bf(a.w);
        r[4] = (short)f2bf(b.x); r[5] = (short)f2bf(b.y);
        r[6] = (short)f2bf(b.z); r[7] = (short)f2bf(b.w);
        return r;
    }
}
template<bool BF>
__device__ __forceinline__ float ldw(const void* __restrict__ p, int i) {
    return BF ? bf2f(((const ushort*)p)[i]) : ((const float*)p)[i];
}
template<bool BF>
__device__ __forceinline__ void stout(void* __restrict__ out, size_t i, float v) {
    if (BF) ((ushort*)out)[i] = f2bf(v);
    else    ((float*)out)[i] = v;
}
__device__ __forceinline__ float fsigm(float x) {
    return __builtin_amdgcn_rcpf(1.f + __expf(-x));
}
__device__ __forceinline__ float ftanh(float x) {
    float e = __expf(-2.f * x);
    return (1.f - e) * __builtin_amdgcn_rcpf(1.f + e);
}

// ================= dtype sniffer =================
__global__ void sniff_kernel(const void* __restrict__ w, int* __restrict__ flag) {
    const unsigned int* p = (const unsigned int*)w;
    int tid = threadIdx.x;
    bool big = false;
    for (int i = tid; i < 512; i += 64) {
        float v = b2f_bits(p[i] << 16);
        if (!(fabsf(v) <= 1.0f)) big = true;   // catches NaN too
    }
    unsigned long long m = __ballot(big);
    if (tid == 0) *flag = (m == 0ull) ? 1 : 0;
}

// ================= speaker chain prep: EV[(b*51+v)][k] = t, CNT[b*51+v] =====
__global__ void spk_prep_kernel(const int* __restrict__ spk,
                                int* __restrict__ EV, int* __restrict__ CNT) {
    const int b = threadIdx.x;            // 64 threads
    if (b >= Bn) return;
    int cloc[51];
    for (int v = 0; v < 51; ++v) cloc[v] = 0;
    for (int t = 0; t < Sn; ++t) {
        const int v = spk[b * Sn + t];
        EV[(b * 51 + v) * Sn + cloc[v]] = t;
        cloc[v]++;
    }
    for (int v = 0; v < 51; ++v) CNT[b * 51 + v] = cloc[v];
}

// ===================================================================
// MFMA 16x16x32 bf16 layouts (m89/m120 verified):
//   A[m = lane&15][k = (lane>>4)*8 + j]
//   B[k = (lane>>4)*8 + j][n = lane&15]
//   D[row = (lane>>4)*4 + reg][col = lane&15]
// 512-thread blocks: 8 waves, wave w owns cols {g*256 + 32w + 16*ctl + c}.
// Invariant (round-9 lesson): each recurrence body keeps EXACTLY ONE weight
// set in registers (192 VGPR) — never stream weights inside a chain.
// ===================================================================

// ---- utterance vocab gate table: Q[v][768] int8, SC[v] f32 ----
template<bool BF>
__device__ void vocab_utt_body(
    const void* __restrict__ emb_u, const void* __restrict__ uWih,
    const void* __restrict__ ubih,
    char* __restrict__ Q, float* __restrict__ SC,
    float* bhs, float (*rmx)[16])
{
    const int tid = threadIdx.x;
    const int w = tid >> 6, l = tid & 63, quad = l >> 4, c = l & 15;

    for (int i = tid; i < 768; i += 512) bhs[i] = ldw<BF>(ubih, i);

    bhalf8 wf[3][2][8];
    #pragma unroll
    for (int g = 0; g < 3; ++g)
        #pragma unroll
        for (int ctl = 0; ctl < 2; ++ctl) {
            const int gcol = g * 256 + 32 * w + 16 * ctl + c;
            #pragma unroll
            for (int tk = 0; tk < 8; ++tk)
                wf[g][ctl][tk] = ldfrag<BF>(uWih, (size_t)gcol * 256 + 32 * tk + 8 * quad);
        }
    __syncthreads();

    for (int vt = blockIdx.x; vt < 2000; vt += gridDim.x) {
        f32x4 acc[3][2];
        #pragma unroll
        for (int g = 0; g < 3; ++g)
            #pragma unroll
            for (int ctl = 0; ctl < 2; ++ctl) {
                float b = bhs[g * 256 + 32 * w + 16 * ctl + c];
                acc[g][ctl] = (f32x4){b, b, b, b};
            }
        #pragma unroll
        for (int tk = 0; tk < 8; ++tk) {
            bhalf8 a = ldfrag<BF>(emb_u, (size_t)(vt * 16 + c) * 256 + 32 * tk + 8 * quad);
            #pragma unroll
            for (int g = 0; g < 3; ++g)
                #pragma unroll
                for (int ctl = 0; ctl < 2; ++ctl)
                    acc[g][ctl] = __builtin_amdgcn_mfma_f32_16x16x32_bf16(
                        a, wf[g][ctl][tk], acc[g][ctl], 0, 0, 0);
        }

        float mx[4];
        #pragma unroll
        for (int r = 0; r < 4; ++r) {
            float v = 0.f;
            #pragma unroll
            for (int g = 0; g < 3; ++g)
                #pragma unroll
                for (int ctl = 0; ctl < 2; ++ctl)
                    v = fmaxf(v, fabsf(acc[g][ctl][r]));
            mx[r] = v;
        }
        #pragma unroll
        for (int off = 1; off < 16; off <<= 1)
            #pragma unroll
            for (int r = 0; r < 4; ++r)
                mx[r] = fmaxf(mx[r], __shfl_xor(mx[r], off));
        if (c == 0)
            #pragma unroll
            for (int r = 0; r < 4; ++r) rmx[w][4 * quad + r] = mx[r];
        __syncthreads();

        #pragma unroll
        for (int r = 0; r < 4; ++r) {
            const int m = 4 * quad + r;
            float s = fmaxf(fmaxf(fmaxf(rmx[0][m], rmx[1][m]), fmaxf(rmx[2][m], rmx[3][m])),
                            fmaxf(fmaxf(rmx[4][m], rmx[5][m]), fmaxf(rmx[6][m], rmx[7][m])));
            float scale = s * (1.f / 127.f);
            float inv   = (s > 0.f) ? (127.f / s) : 0.f;
            #pragma unroll
            for (int g = 0; g < 3; ++g)
                #pragma unroll
                for (int ctl = 0; ctl < 2; ++ctl) {
                    int qv = __float2int_rn(acc[g][ctl][r] * inv);
                    qv = max(-127, min(127, qv));
                    Q[(size_t)(vt * 16 + m) * 768 + g * 256 + 32 * w + 16 * ctl + c] = (char)qv;
                }
            if (w == 0 && c == 0) SC[vt * 16 + m] = scale;
        }
        __syncthreads();
    }
}

__global__ __launch_bounds__(512, 1) void vocab_utt_kernel(
    const void* emb_u, const void* uWih, const void* ubih,
    char* Q, float* SC, const int* flag)
{
    __shared__ float bhs[768];
    __shared__ float rmx[8][16];
    if (*flag) vocab_utt_body<true >(emb_u, uWih, ubih, Q, SC, bhs, rmx);
    else       vocab_utt_body<false>(emb_u, uWih, ubih, Q, SC, bhs, rmx);
}

// ---- utterance GRU recurrence: 200 blocks x 16 seqs (512 thr, dbuf, async prefetch) ----
template<bool BF>
__device__ void rec_utt_body(
    const int* __restrict__ ctx_tok,
    const char* __restrict__ Q, const float* __restrict__ SC,
    const void* __restrict__ uWhh, const void* __restrict__ ubhh,
    ushort* __restrict__ H_u,
    char (*gq)[16][784], float* gsc_all /*[Tn*16]*/, ushort (*hb)[16][264])
{
    const int n0 = blockIdx.x * 16;
    const int tid = threadIdx.x;
    const int w = tid >> 6, l = tid & 63, quad = l >> 4, c = l & 15;

    for (int i = tid; i < 16 * 264; i += 512) (&hb[0][0][0])[i] = 0;
    // all 800 per-token scales up-front
    for (int i = tid; i < Tn * 16; i += 512) {
        const int t = i >> 4, m = i & 15;
        gsc_all[i] = SC[ctx_tok[(n0 + m) * Tn + t]];
    }

    float breg[3][2];
    #pragma unroll
    for (int g = 0; g < 3; ++g)
        #pragma unroll
        for (int ctl = 0; ctl < 2; ++ctl)
            breg[g][ctl] = ldw<BF>(ubhh, g * 256 + 32 * w + 16 * ctl + c);

    bhalf8 wf[3][2][8];
    #pragma unroll
    for (int g = 0; g < 3; ++g)
        #pragma unroll
        for (int ctl = 0; ctl < 2; ++ctl) {
            const int gcol = g * 256 + 32 * w + 16 * ctl + c;
            #pragma unroll
            for (int tk = 0; tk < 8; ++tk)
                wf[g][ctl][tk] = ldfrag<BF>(uWhh, (size_t)gcol * 256 + 32 * tk + 8 * quad);
        }

    float st[2][4];
    #pragma unroll
    for (int ctl = 0; ctl < 2; ++ctl)
        #pragma unroll
        for (int r = 0; r < 4; ++r) st[ctl][r] = 0.f;

    // preload gi(0) into buffer 0: wave w copies rows {2w, 2w+1}, 768 B each
    #pragma unroll
    for (int k = 0; k < 2; ++k) {
        const int m = 2 * w + k;
        const int tok = ctx_tok[(n0 + m) * Tn + 0];
        if (l < 48)
            gld_lds16(Q + (size_t)tok * 768 + l * 16, &gq[0][m][0]);
    }
    __syncthreads();

    int p = 0;
    for (int t = 0; t < Tn; ++t) {
        // async prefetch of gi(t+1) into the other buffer (no registers held)
        if (t < Tn - 1) {
            #pragma unroll
            for (int k = 0; k < 2; ++k) {
                const int m = 2 * w + k;
                const int tok = ctx_tok[(n0 + m) * Tn + t + 1];
                if (l < 48)
                    gld_lds16(Q + (size_t)tok * 768 + l * 16, &gq[p ^ 1][m][0]);
            }
        }

        f32x4 acc[3][2];
        #pragma unroll
        for (int g = 0; g < 3; ++g)
            #pragma unroll
            for (int ctl = 0; ctl < 2; ++ctl) {
                float b = breg[g][ctl];
                acc[g][ctl] = (f32x4){b, b, b, b};
            }
        #pragma unroll
        for (int tk = 0; tk < 8; ++tk) {
            bhalf8 a = *(const bhalf8*)(&hb[p][c][32 * tk + 8 * quad]);
            #pragma unroll
            for (int g = 0; g < 3; ++g)
                #pragma unroll
                for (int ctl = 0; ctl < 2; ++ctl)
                    acc[g][ctl] = __builtin_amdgcn_mfma_f32_16x16x32_bf16(
                        a, wf[g][ctl][tk], acc[g][ctl], 0, 0, 0);
        }

        #pragma unroll
        for (int ctl = 0; ctl < 2; ++ctl) {
            const int u = 32 * w + 16 * ctl + c;
            #pragma unroll
            for (int r = 0; r < 4; ++r) {
                const int m = 4 * quad + r;
                const float s = gsc_all[t * 16 + m];
                float gr = s * (float)(signed char)gq[p][m][u];
                float gz = s * (float)(signed char)gq[p][m][256 + u];
                float gn = s * (float)(signed char)gq[p][m][512 + u];
                float rr = fsigm(gr + acc[0][ctl][r]);
                float zz = fsigm(gz + acc[1][ctl][r]);
                float nn = ftanh(gn + rr * acc[2][ctl][r]);
                float h  = (1.f - zz) * nn + zz * st[ctl][r];
                st[ctl][r] = h;
                hb[p ^ 1][m][u] = f2bf(h);
            }
        }
        __syncthreads();   // drains lds writes AND the async copies
        p ^= 1;
    }

    #pragma unroll
    for (int ctl = 0; ctl < 2; ++ctl)
        #pragma unroll
        for (int r = 0; r < 4; ++r)
            H_u[(size_t)(n0 + 4 * quad + r) * Hn + 32 * w + 16 * ctl + c] = f2bf(st[ctl][r]);
}

__global__ __launch_bounds__(512, 1) void rec_utt_kernel(
    const int* ctx_tok, const char* Q, const float* SC,
    const void* uWhh, const void* ubhh, ushort* H_u, const int* flag)
{
    __shared__ __align__(16) char   gq[2][16][784];
    __shared__ float  gsc_all[Tn * 16];
    __shared__ __align__(16) ushort hb[2][16][264];
    if (*flag) rec_utt_body<true >(ctx_tok, Q, SC, uWhh, ubhh, H_u, gq, gsc_all, hb);
    else       rec_utt_body<false>(ctx_tok, Q, SC, uWhh, ubhh, H_u, gq, gsc_all, hb);
}

// ---- response per-instance gates: RG[inst][768] bf16 (inst = n*50+t) ----
template<bool BF>
__device__ void respgi_body(
    int bid,
    const int* __restrict__ rsp_tok, const void* __restrict__ emb_r,
    const void* __restrict__ rWih, const void* __restrict__ rbih,
    ushort* __restrict__ RG, float* bhs)
{
    const int tid = threadIdx.x;
    const int w = tid >> 6, l = tid & 63, quad = l >> 4, c = l & 15;

    for (int i = tid; i < 768; i += 512) bhs[i] = ldw<BF>(rbih, i);

    bhalf8 wf[3][2][8];
    #pragma unroll
    for (int g = 0; g < 3; ++g)
        #pragma unroll
        for (int ctl = 0; ctl < 2; ++ctl) {
            const int gcol = g * 256 + 32 * w + 16 * ctl + c;
            #pragma unroll
            for (int tk = 0; tk < 8; ++tk)
                wf[g][ctl][tk] = ldfrag<BF>(rWih, (size_t)gcol * 256 + 32 * tk + 8 * quad);
        }
    __syncthreads();

    const int inst = bid * 16 + c;      // 6400 instances / 16 per block
    const int tok  = rsp_tok[inst];

    f32x4 acc[3][2];
    #pragma unroll
    for (int g = 0; g < 3; ++g)
        #pragma unroll
        for (int ctl = 0; ctl < 2; ++ctl) {
            float b = bhs[g * 256 + 32 * w + 16 * ctl + c];
            acc[g][ctl] = (f32x4){b, b, b, b};
        }
    #pragma unroll
    for (int tk = 0; tk < 8; ++tk) {
        bhalf8 a = ldfrag<BF>(emb_r, (size_t)tok * 256 + 32 * tk + 8 * quad);
        #pragma unroll
        for (int g = 0; g < 3; ++g)
            #pragma unroll
            for (int ctl = 0; ctl < 2; ++ctl)
                acc[g][ctl] = __builtin_amdgcn_mfma_f32_16x16x32_bf16(
                    a, wf[g][ctl][tk], acc[g][ctl], 0, 0, 0);
    }
    #pragma unroll
    for (int g = 0; g < 3; ++g)
        #pragma unroll
        for (int ctl = 0; ctl < 2; ++ctl)
            #pragma unroll
            for (int r = 0; r < 4; ++r)
                RG[(size_t)(bid * 16 + 4 * quad + r) * 768
                   + g * 256 + 32 * w + 16 * ctl + c] = f2bf(acc[g][ctl][r]);
}

// ---- response GRU recurrence body: 8 blocks x 16 seqs (512 thr, dbuf) ----
template<bool BF>
__device__ void rec_resp_body(
    int bid,
    const ushort* __restrict__ RG,
    const void* __restrict__ rWhh, const void* __restrict__ rbhh,
    void* __restrict__ outp,
    ushort (*gx)[16][776], ushort (*hb)[16][264])
{
    const int n0 = bid * 16;
    const int tid = threadIdx.x;
    const int w = tid >> 6, l = tid & 63, quad = l >> 4, c = l & 15;

    for (int i = tid; i < 16 * 264; i += 512) (&hb[0][0][0])[i] = 0;

    float breg[3][2];
    #pragma unroll
    for (int g = 0; g < 3; ++g)
        #pragma unroll
        for (int ctl = 0; ctl < 2; ++ctl)
            breg[g][ctl] = ldw<BF>(rbhh, g * 256 + 32 * w + 16 * ctl + c);

    bhalf8 wf[3][2][8];
    #pragma unroll
    for (int g = 0; g < 3; ++g)
        #pragma unroll
        for (int ctl = 0; ctl < 2; ++ctl) {
            const int gcol = g * 256 + 32 * w + 16 * ctl + c;
            #pragma unroll
            for (int tk = 0; tk < 8; ++tk)
                wf[g][ctl][tk] = ldfrag<BF>(rWhh, (size_t)gcol * 256 + 32 * tk + 8 * quad);
        }

    float st[2][4];
    #pragma unroll
    for (int ctl = 0; ctl < 2; ++ctl)
        #pragma unroll
        for (int r = 0; r < 4; ++r) st[ctl][r] = 0.f;

    // preload gi(0): wave w copies rows {2w, 2w+1}, 1536 B each (2 chunks)
    #pragma unroll
    for (int k = 0; k < 2; ++k) {
        const int m = 2 * w + k;
        const ushort* src = RG + (size_t)((n0 + m) * Tn + 0) * 768;
        if (l < 48) {
            gld_lds16(src + l * 8,       &gx[0][m][0]);
            gld_lds16(src + 384 + l * 8, &gx[0][m][384]);
        }
    }
    __syncthreads();

    int p = 0;
    for (int t = 0; t < Tn; ++t) {
        // async prefetch of gi(t+1)
        if (t < Tn - 1) {
            #pragma unroll
            for (int k = 0; k < 2; ++k) {
                const int m = 2 * w + k;
                const ushort* src = RG + (size_t)((n0 + m) * Tn + t + 1) * 768;
                if (l < 48) {
                    gld_lds16(src + l * 8,       &gx[p ^ 1][m][0]);
                    gld_lds16(src + 384 + l * 8, &gx[p ^ 1][m][384]);
                }
            }
        }
        // deferred store of h(t-1): full step to retire before the barrier drain
        if (t > 0) {
            #pragma unroll
            for (int ctl = 0; ctl < 2; ++ctl) {
                const int u = 32 * w + 16 * ctl + c;
                #pragma unroll
                for (int r = 0; r < 4; ++r) {
                    const int n = n0 + 4 * quad + r, bb = n >> 1, ri = n & 1;
                    stout<BF>(outp, OFF_RESP_OUT
                              + (size_t)((ri * Tn + (t - 1)) * Bn + bb) * Hn + u,
                              st[ctl][r]);
                }
            }
        }

        f32x4 acc[3][2];
        #pragma unroll
        for (int g = 0; g < 3; ++g)
            #pragma unroll
            for (int ctl = 0; ctl < 2; ++ctl) {
                float b = breg[g][ctl];
                acc[g][ctl] = (f32x4){b, b, b, b};
            }
        #pragma unroll
        for (int tk = 0; tk < 8; ++tk) {
            bhalf8 a = *(const bhalf8*)(&hb[p][c][32 * tk + 8 * quad]);
            #pragma unroll
            for (int g = 0; g < 3; ++g)
                #pragma unroll
                for (int ctl = 0; ctl < 2; ++ctl)
                    acc[g][ctl] = __builtin_amdgcn_mfma_f32_16x16x32_bf16(
                        a, wf[g][ctl][tk], acc[g][ctl], 0, 0, 0);
        }

        #pragma unroll
        for (int ctl = 0; ctl < 2; ++ctl) {
            const int u = 32 * w + 16 * ctl + c;
            #pragma unroll
            for (int r = 0; r < 4; ++r) {
                const int m = 4 * quad + r;
                float gr = bf2f(gx[p][m][u]);
                float gz = bf2f(gx[p][m][256 + u]);
                float gn = bf2f(gx[p][m][512 + u]);
                float rr = fsigm(gr + acc[0][ctl][r]);
                float zz = fsigm(gz + acc[1][ctl][r]);
                float nn = ftanh(gn + rr * acc[2][ctl][r]);
                float h  = (1.f - zz) * nn + zz * st[ctl][r];
                st[ctl][r] = h;
                hb[p ^ 1][m][u] = f2bf(h);
            }
        }
        __syncthreads();
        p ^= 1;
    }

    // final stores: h(49) -> resp_out[t=49] and resp_hid
    #pragma unroll
    for (int ctl = 0; ctl < 2; ++ctl) {
        const int u = 32 * w + 16 * ctl + c;
        #pragma unroll
        for (int r = 0; r < 4; ++r) {
            const int n = n0 + 4 * quad + r, bb = n >> 1, ri = n & 1;
            stout<BF>(outp, OFF_RESP_OUT
                      + (size_t)((ri * Tn + (Tn - 1)) * Bn + bb) * Hn + u, st[ctl][r]);
            stout<BF>(outp, OFF_RESP_HID + (size_t)(ri * Bn + bb) * Hn + u, st[ctl][r]);
        }
    }
}

// ============ ctx input gates (MFMA, K=512 in two passes): 200 blocks x 16 rows ============
template<bool BF>
__device__ void gi_ctx_body(
    int bid,
    const ushort* __restrict__ H_u, const ushort* __restrict__ tblbf,
    const int* __restrict__ spk_agents,
    const void* __restrict__ Wih, const void* __restrict__ bih,
    ushort* __restrict__ GIc, float* bhs)
{
    const int tid = threadIdx.x;
    const int w = tid >> 6, l = tid & 63, quad = l >> 4, c = l & 15;

    for (int i = tid; i < 768; i += 512) bhs[i] = ldw<BF>(bih, i);
    __syncthreads();

    // A row for lane c: m = m0+c (m = s*64+b)
    const int m0 = bid * 16;
    const int m  = m0 + c, s = m >> 6, b = m & 63;
    const int a  = spk_agents[b * Sn + s];
    const ushort* arow0 = H_u   + (size_t)(b * Sn + s) * Hn;   // k in [0,256)
    const ushort* arow1 = tblbf + (size_t)(b * 51 + a) * Hn;   // k in [256,512)

    f32x4 acc[3][2];
    #pragma unroll
    for (int g = 0; g < 3; ++g)
        #pragma unroll
        for (int ctl = 0; ctl < 2; ++ctl) {
            float bb = bhs[g * 256 + 32 * w + 16 * ctl + c];
            acc[g][ctl] = (f32x4){bb, bb, bb, bb};
        }

    for (int half = 0; half < 2; ++half) {
        const ushort* ar = half ? arow1 : arow0;
        bhalf8 af[8];
        #pragma unroll
        for (int tk = 0; tk < 8; ++tk)
            af[tk] = *(const bhalf8*)(ar + 32 * tk + 8 * quad);
        #pragma unroll
        for (int g = 0; g < 3; ++g) {
            bhalf8 wfl[2][8];
            #pragma unroll
            for (int ctl = 0; ctl < 2; ++ctl) {
                const int gcol = g * 256 + 32 * w + 16 * ctl + c;
                #pragma unroll
                for (int tk = 0; tk < 8; ++tk)
                    wfl[ctl][tk] = ldfrag<BF>(Wih,
                        (size_t)gcol * 512 + half * 256 + 32 * tk + 8 * quad);
            }
            #pragma unroll
            for (int tk = 0; tk < 8; ++tk)
                #pragma unroll
                for (int ctl = 0; ctl < 2; ++ctl)
                    acc[g][ctl] = __builtin_amdgcn_mfma_f32_16x16x32_bf16(
                        af[tk], wfl[ctl][tk], acc[g][ctl], 0, 0, 0);
        }
    }

    #pragma unroll
    for (int g = 0; g < 3; ++g)
        #pragma unroll
        for (int ctl = 0; ctl < 2; ++ctl)
            #pragma unroll
            for (int r = 0; r < 4; ++r)
                GIc[(size_t)(m0 + 4 * quad + r) * 768
                    + g * 256 + 32 * w + 16 * ctl + c] = f2bf(acc[g][ctl][r]);
}

// ============ fused gate kernel: respgi (blocks 0..399) ∪ gi_ctx (400..599) ============
__global__ __launch_bounds__(512, 1) void gates2_kernel(
    const int* rsp_tok, const void* emb_r, const void* rWih, const void* rbih,
    ushort* RG,
    const ushort* H_u, const ushort* tblbf, const int* spk_agents,
    const void* cWih, const void* cbih, ushort* GIc, const int* flag)
{
    __shared__ float bhs[768];
    if (blockIdx.x < 400) {
        if (*flag) respgi_body<true >(blockIdx.x, rsp_tok, emb_r, rWih, rbih, RG, bhs);
        else       respgi_body<false>(blockIdx.x, rsp_tok, emb_r, rWih, rbih, RG, bhs);
    } else {
        const int bid = blockIdx.x - 400;
        if (*flag) gi_ctx_body<true >(bid, H_u, tblbf, spk_agents, cWih, cbih, GIc, bhs);
        else       gi_ctx_body<false>(bid, H_u, tblbf, spk_agents, cWih, cbih, GIc, bhs);
    }
}

// ============ context GRU recurrence body (MFMA): 4 blocks x 16 batches (512 thr, dbuf) ============
template<bool BF>
__device__ void ctx_rec_body(
    int bid,
    const ushort* __restrict__ GIc,     // bf16 [3200][768], row = s*64+b
    const void* __restrict__ Whh, const void* __restrict__ bhh,
    float* __restrict__ CO, void* __restrict__ outp,
    ushort (*gx)[16][776], ushort (*hb)[16][264])
{
    const int n0 = bid * 16;
    const int tid = threadIdx.x;
    const int w = tid >> 6, l = tid & 63, quad = l >> 4, c = l & 15;

    for (int i = tid; i < 16 * 264; i += 512) (&hb[0][0][0])[i] = 0;

    float breg[3][2];
    #pragma unroll
    for (int g = 0; g < 3; ++g)
        #pragma unroll
        for (int ctl = 0; ctl < 2; ++ctl)
            breg[g][ctl] = ldw<BF>(bhh, g * 256 + 32 * w + 16 * ctl + c);

    bhalf8 wf[3][2][8];
    #pragma unroll
    for (int g = 0; g < 3; ++g)
        #pragma unroll
        for (int ctl = 0; ctl < 2; ++ctl) {
            const int gcol = g * 256 + 32 * w + 16 * ctl + c;
            #pragma unroll
            for (int tk = 0; tk < 8; ++tk)
                wf[g][ctl][tk] = ldfrag<BF>(Whh, (size_t)gcol * 256 + 32 * tk + 8 * quad);
        }

    float st[2][4];
    #pragma unroll
    for (int ctl = 0; ctl < 2; ++ctl)
        #pragma unroll
        for (int r = 0; r < 4; ++r) st[ctl][r] = 0.f;

    // preload gi(0): wave w copies rows {2w, 2w+1}
    #pragma unroll
    for (int k = 0; k < 2; ++k) {
        const int m = 2 * w + k;
        const ushort* src = GIc + (size_t)(0 * Bn + n0 + m) * 768;
        if (l < 48) {
            gld_lds16(src + l * 8,       &gx[0][m][0]);
            gld_lds16(src + 384 + l * 8, &gx[0][m][384]);
        }
    }
    __syncthreads();

    int p = 0;
    for (int t = 0; t < Sn; ++t) {
        // async prefetch of gi(t+1)
        if (t < Sn - 1) {
            #pragma unroll
            for (int k = 0; k < 2; ++k) {
                const int m = 2 * w + k;
                const ushort* src = GIc + (size_t)((t + 1) * Bn + n0 + m) * 768;
                if (l < 48) {
                    gld_lds16(src + l * 8,       &gx[p ^ 1][m][0]);
                    gld_lds16(src + 384 + l * 8, &gx[p ^ 1][m][384]);
                }
            }
        }
        // deferred stores of h(t-1)
        if (t > 0) {
            #pragma unroll
            for (int ctl = 0; ctl < 2; ++ctl) {
                const int u = 32 * w + 16 * ctl + c;
                #pragma unroll
                for (int r = 0; r < 4; ++r) {
                    const size_t gri = (size_t)((t - 1) * Bn + n0 + 4 * quad + r);
                    CO[gri * Hn + u] = st[ctl][r];
                    stout<BF>(outp, OFF_CTX_OUT + gri * Hn + u, st[ctl][r]);
                }
            }
        }

        f32x4 acc[3][2];
        #pragma unroll
        for (int g = 0; g < 3; ++g)
            #pragma unroll
            for (int ctl = 0; ctl < 2; ++ctl) {
                float b = breg[g][ctl];
                acc[g][ctl] = (f32x4){b, b, b, b};
            }
        #pragma unroll
        for (int tk = 0; tk < 8; ++tk) {
            bhalf8 a = *(const bhalf8*)(&hb[p][c][32 * tk + 8 * quad]);
            #pragma unroll
            for (int g = 0; g < 3; ++g)
                #pragma unroll
                for (int ctl = 0; ctl < 2; ++ctl)
                    acc[g][ctl] = __builtin_amdgcn_mfma_f32_16x16x32_bf16(
                        a, wf[g][ctl][tk], acc[g][ctl], 0, 0, 0);
        }

        #pragma unroll
        for (int ctl = 0; ctl < 2; ++ctl) {
            const int u = 32 * w + 16 * ctl + c;
            #pragma unroll
            for (int r = 0; r < 4; ++r) {
                const int m = 4 * quad + r;
                float gr = bf2f(gx[p][m][u]);
                float gz = bf2f(gx[p][m][256 + u]);
                float gn = bf2f(gx[p][m][512 + u]);
                float rr = fsigm(gr + acc[0][ctl][r]);
                float zz = fsigm(gz + acc[1][ctl][r]);
                float nn = ftanh(gn + rr * acc[2][ctl][r]);
                float h  = (1.f - zz) * nn + zz * st[ctl][r];
                st[ctl][r] = h;
                hb[p ^ 1][m][u] = f2bf(h);
            }
        }
        __syncthreads();
        p ^= 1;
    }

    // final stores: h(49) -> CO, ctx_out, ctx_hid
    #pragma unroll
    for (int ctl = 0; ctl < 2; ++ctl) {
        const int u = 32 * w + 16 * ctl + c;
        #pragma unroll
        for (int r = 0; r < 4; ++r) {
            const int m = 4 * quad + r;
            const size_t gri = (size_t)((Sn - 1) * Bn + n0 + m);
            CO[gri * Hn + u] = st[ctl][r];
            stout<BF>(outp, OFF_CTX_OUT + gri * Hn + u, st[ctl][r]);
            stout<BF>(outp, OFF_CTX_HID + (size_t)(n0 + m) * Hn + u, st[ctl][r]);
        }
    }
}

// ============ fused recurrence kernel: ctx_rec (blocks 0..3) ∪ rec_resp (4..11) ============
__global__ __launch_bounds__(512, 1) void rec2_kernel(
    const ushort* GIc, const void* cWhh, const void* cbhh, float* CO,
    const ushort* RG, const void* rWhh, const void* rbhh,
    void* outp, const int* flag)
{
    __shared__ __align__(16) ushort gx[2][16][776];
    __shared__ __align__(16) ushort hb[2][16][264];
    if (blockIdx.x < 4) {
        if (*flag) ctx_rec_body<true >(blockIdx.x, GIc, cWhh, cbhh, CO, outp, gx, hb);
        else       ctx_rec_body<false>(blockIdx.x, GIc, cWhh, cbhh, CO, outp, gx, hb);
    } else {
        const int bid = blockIdx.x - 4;
        if (*flag) rec_resp_body<true >(bid, RG, rWhh, rbhh, outp, gx, hb);
        else       rec_resp_body<false>(bid, RG, rWhh, rbhh, outp, gx, hb);
    }
}

// ============ spk input gates (MFMA, respgi clone): 200 blocks x 16 rows ============
template<bool BF>
__device__ void gi_spk_body(
    const float* __restrict__ CO,       // f32 [3200][256]
    const void* __restrict__ Wih, const void* __restrict__ bih,
    ushort* __restrict__ GIs, float* bhs)
{
    const int tid = threadIdx.x;
    const int w = tid >> 6, l = tid & 63, quad = l >> 4, c = l & 15;

    for (int i = tid; i < 768; i += 512) bhs[i] = ldw<BF>(bih, i);

    bhalf8 wf[3][2][8];
    #pragma unroll
    for (int g = 0; g < 3; ++g)
        #pragma unroll
        for (int ctl = 0; ctl < 2; ++ctl) {
            const int gcol = g * 256 + 32 * w + 16 * ctl + c;
            #pragma unroll
            for (int tk = 0; tk < 8; ++tk)
                wf[g][ctl][tk] = ldfrag<BF>(Wih, (size_t)gcol * 256 + 32 * tk + 8 * quad);
        }
    __syncthreads();

    f32x4 acc[3][2];
    #pragma unroll
    for (int g = 0; g < 3; ++g)
        #pragma unroll
        for (int ctl = 0; ctl < 2; ++ctl) {
            float b = bhs[g * 256 + 32 * w + 16 * ctl + c];
            acc[g][ctl] = (f32x4){b, b, b, b};
        }
    #pragma unroll
    for (int tk = 0; tk < 8; ++tk) {
        bhalf8 a = ldfrag<false>(CO, (size_t)(blockIdx.x * 16 + c) * 256 + 32 * tk + 8 * quad);
        #pragma unroll
        for (int g = 0; g < 3; ++g)
            #pragma unroll
            for (int ctl = 0; ctl < 2; ++ctl)
                acc[g][ctl] = __builtin_amdgcn_mfma_f32_16x16x32_bf16(
                    a, wf[g][ctl][tk], acc[g][ctl], 0, 0, 0);
    }
    #pragma unroll
    for (int g = 0; g < 3; ++g)
        #pragma unroll
        for (int ctl = 0; ctl < 2; ++ctl)
            #pragma unroll
            for (int r = 0; r < 4; ++r)
                GIs[(size_t)(blockIdx.x * 16 + 4 * quad + r) * 768
                    + g * 256 + 32 * w + 16 * ctl + c] = f2bf(acc[g][ctl][r]);
}

__global__ __launch_bounds__(512, 1) void gi_spk_kernel(
    const float* CO, const void* Wih, const void* bih, ushort* GIs, const int* flag)
{
    __shared__ float bhs[768];
    if (*flag) gi_spk_body<true >(CO, Wih, bih, GIs, bhs);
    else       gi_spk_body<false>(CO, Wih, bih, GIs, bhs);
}

// ============ speaker chain GRU: 204 blocks x 16 chains (512 thr) ============
// Chain ci = b*51+v evolves only at its own timesteps EV[ci][0..CNT[ci]).
// Per block: 16 chains in MFMA lockstep for Kmax = max(CNT) steps; sWhh in
// registers (192 VGPR, one weight set — the invariant); gate rows gathered
// from GIs by event time.  h lives in fp32 registers across chain steps.
template<bool BF>
__device__ void spk_chain_body(
    const ushort* __restrict__ GIs,     // bf16 [3200][768], row = t*64+b
    const void* __restrict__ Whh, const void* __restrict__ bhh,
    const int* __restrict__ EV, const int* __restrict__ CNT,
    void* __restrict__ outp,
    ushort (*gx)[16][776], ushort (*hb)[16][264], int* cnts)
{
    const int ci0 = blockIdx.x * 16;
    const int tid = threadIdx.x;
    const int w = tid >> 6, l = tid & 63, quad = l >> 4, c = l & 15;

    for (int i = tid; i < 16 * 264; i += 512) (&hb[0][0][0])[i] = 0;
    if (tid < 16) cnts[tid] = CNT[ci0 + tid];

    float breg[3][2];
    #pragma unroll
    for (int g = 0; g < 3; ++g)
        #pragma unroll
        for (int ctl = 0; ctl < 2; ++ctl)
            breg[g][ctl] = ldw<BF>(bhh, g * 256 + 32 * w + 16 * ctl + c);

    bhalf8 wf[3][2][8];
    #pragma unroll
    for (int g = 0; g < 3; ++g)
        #pragma unroll
        for (int ctl = 0; ctl < 2; ++ctl) {
            const int gcol = g * 256 + 32 * w + 16 * ctl + c;
            #pragma unroll
            for (int tk = 0; tk < 8; ++tk)
                wf[g][ctl][tk] = ldfrag<BF>(Whh, (size_t)gcol * 256 + 32 * tk + 8 * quad);
        }

    float st[2][4];
    #pragma unroll
    for (int ctl = 0; ctl < 2; ++ctl)
        #pragma unroll
        for (int r = 0; r < 4; ++r) st[ctl][r] = 0.f;

    __syncthreads();   // cnts + hb zero visible

    int Kmax = 0;
    #pragma unroll
    for (int m = 0; m < 16; ++m) Kmax = max(Kmax, cnts[m]);

    if (Kmax > 0) {
        // preload gate rows for k=0: wave w handles rows {2w, 2w+1}
        #pragma unroll
        for (int k0 = 0; k0 < 2; ++k0) {
            const int m = 2 * w + k0, ci = ci0 + m, b = ci / 51;
            const int te = (cnts[m] > 0) ? EV[ci * Sn + 0] : 0;
            const ushort* src = GIs + (size_t)(te * Bn + b) * 768;
            if (l < 48) {
                gld_lds16(src + l * 8,       &gx[0][m][0]);
                gld_lds16(src + 384 + l * 8, &gx[0][m][384]);
            }
        }
        __syncthreads();

        int p = 0;
        for (int k = 0; k < Kmax; ++k) {
            // async prefetch of event k+1 rows
            if (k < Kmax - 1) {
                #pragma unroll
                for (int k0 = 0; k0 < 2; ++k0) {
                    const int m = 2 * w + k0, ci = ci0 + m, b = ci / 51;
                    const int te = (k + 1 < cnts[m]) ? EV[ci * Sn + k + 1] : 0;
                    const ushort* src = GIs + (size_t)(te * Bn + b) * 768;
                    if (l < 48) {
                        gld_lds16(src + l * 8,       &gx[p ^ 1][m][0]);
                        gld_lds16(src + 384 + l * 8, &gx[p ^ 1][m][384]);
                    }
                }
            }

            f32x4 acc[3][2];
            #pragma unroll
            for (int g = 0; g < 3; ++g)
                #pragma unroll
                for (int ctl = 0; ctl < 2; ++ctl) {
                    float b = breg[g][ctl];
                    acc[g][ctl] = (f32x4){b, b, b, b};
                }
            #pragma unroll
            for (int tk = 0; tk < 8; ++tk) {
                bhalf8 a = *(const bhalf8*)(&hb[p][c][32 * tk + 8 * quad]);
                #pragma unroll
                for (int g = 0; g < 3; ++g)
                    #pragma unroll
                    for (int ctl = 0; ctl < 2; ++ctl)
                        acc[g][ctl] = __builtin_amdgcn_mfma_f32_16x16x32_bf16(
                            a, wf[g][ctl][tk], acc[g][ctl], 0, 0, 0);
            }

            #pragma unroll
            for (int ctl = 0; ctl < 2; ++ctl) {
                const int u = 32 * w + 16 * ctl + c;
                #pragma unroll
                for (int r = 0; r < 4; ++r) {
                    const int m = 4 * quad + r;
                    const bool act = (k < cnts[m]);
                    float gr = bf2f(gx[p][m][u]);
                    float gz = bf2f(gx[p][m][256 + u]);
                    float gn = bf2f(gx[p][m][512 + u]);
                    float rr = fsigm(gr + acc[0][ctl][r]);
                    float zz = fsigm(gz + acc[1][ctl][r]);
                    float nn = ftanh(gn + rr * acc[2][ctl][r]);
                    float h  = (1.f - zz) * nn + zz * st[ctl][r];
                    st[ctl][r] = act ? h : st[ctl][r];
                    hb[p ^ 1][m][u] = f2bf(st[ctl][r]);
                }
            }
            __syncthreads();
            p ^= 1;
        }
    }

    // outputs: spk_emb rows (empty chains write zeros) + mask
    #pragma unroll
    for (int ctl = 0; ctl < 2; ++ctl) {
        const int u = 32 * w + 16 * ctl + c;
        #pragma unroll
        for (int r = 0; r < 4; ++r) {
            const int ci = ci0 + 4 * quad + r;
            stout<BF>(outp, OFF_SPK_EMB + (size_t)ci * Hn + u, st[ctl][r]);
        }
    }
    if (tid < 16) {
        const int ci = ci0 + tid, v = ci % 51;
        stout<BF>(outp, OFF_SPK_MASK + (size_t)ci,
                  (cnts[tid] > 0 && v > 0) ? 1.f : 0.f);
    }
}

__global__ __launch_bounds__(512, 1) void spk_chain_kernel(
    const ushort* GIs, const void* Whh, const void* bhh,
    const int* EV, const int* CNT, void* outp, const int* flag)
{
    __shared__ __align__(16) ushort gx[2][16][776];
    __shared__ __align__(16) ushort hb[2][16][264];
    __shared__ int cnts[16];
    if (*flag) spk_chain_body<true >(GIs, Whh, bhh, EV, CNT, outp, gx, hb, cnts);
    else       spk_chain_body<false>(GIs, Whh, bhh, EV, CNT, outp, gx, hb, cnts);
}

// ================= host-side MT19937 (numpy legacy RandomState, seed 1) =================
namespace {
inline uint16_t host_f2bf(float f) {
    union { float f; uint32_t u; } c; c.f = f;
    return (uint16_t)((c.u + 0x7fffu + ((c.u >> 16) & 1u)) >> 16);
}
struct MT19937 {
    uint32_t mt[624]; int mti;
    void seed(uint32_t s) {
        mt[0] = s;
        for (int i = 1; i < 624; ++i)
            mt[i] = 1812433253u * (mt[i - 1] ^ (mt[i - 1] >> 30)) + (uint32_t)i;
        mti = 624;
    }
    uint32_t next() {
        if (mti >= 624) {
            for (int i = 0; i < 624; ++i) {
                uint32_t y = (mt[i] & 0x80000000u) | (mt[(i + 1) % 624] & 0x7fffffffu);
                mt[i] = mt[(i + 397) % 624] ^ (y >> 1) ^ ((y & 1u) ? 0x9908b0dfu : 0u);
            }
            mti = 0;
        }
        uint32_t y = mt[mti++];
        y ^= y >> 11; y ^= (y << 7) & 0x9d2c5680u; y ^= (y << 15) & 0xefc60000u; y ^= y >> 18;
        return y;
    }
    double rd() {
        uint32_t a = next() >> 5, b = next() >> 6;
        return (a * 67108864.0 + b) / 9007199254740992.0;
    }
};

uint16_t* get_host_tables() {      // bf16 bits (feeds MFMA A-fragments)
    static uint16_t* p = [] {
        void* q = nullptr;
        if (hipHostMalloc(&q, 835584 * sizeof(uint16_t), hipHostMallocDefault) != hipSuccess)
            q = malloc(835584 * sizeof(uint16_t));
        uint16_t* h = (uint16_t*)q;
        MT19937 g; g.seed(1u);
        for (int i = 0; i < 835584; ++i)
            h[i] = host_f2bf((float)g.rd());
        return h;
    }();
    return p;
}
} // namespace

// ================= launch =================
extern "C" void kernel_launch(void* const* d_in, const int* in_sizes, int n_in,
                              void* d_out, int out_size, void* d_ws, size_t ws_size,
                              hipStream_t stream)
{
    const int* ctx_tok    = (const int*)d_in[0];
    const int* rsp_tok    = (const int*)d_in[1];
    const int* spk_agents = (const int*)d_in[2];
    const void* emb_u = d_in[3];
    const void* emb_r = d_in[4];
    const void* uWih = d_in[5],  *uWhh = d_in[6],  *ubih = d_in[7],  *ubhh = d_in[8];
    const void* cWih = d_in[9],  *cWhh = d_in[10], *cbih = d_in[11], *cbhh = d_in[12];
    const void* rWih = d_in[13], *rWhh = d_in[14], *rbih = d_in[15], *rbhh = d_in[16];
    const void* sWih = d_in[17], *sWhh = d_in[18], *sbih = d_in[19], *sbhh = d_in[20];
    (void)in_sizes; (void)n_in; (void)out_size; (void)ws_size;

    char* ws  = (char*)d_ws;
    char* reg = ws + WS_REG;
    int*      flag = (int*)(ws + WS_FLAG);
    ushort*   H_u  = (ushort*)(ws + WS_HU);
    char*     UQ   = (char*)(reg + RG_UTTQ);
    float*    USC  = (float*)(reg + RG_UTTSC);
    ushort*   RG   = (ushort*)(reg + RG_RESPGI);
    float*    CO   = (float*)(reg + RG_CO);
    ushort*   GIc  = (ushort*)(reg + RG_GIC);
    ushort*   GIs  = (ushort*)(reg + RG_GIS);
    ushort*   tbl  = (ushort*)(reg + RG_TBL);
    int*      EV   = (int*)(ws + WS_EV);
    int*      CNT  = (int*)(ws + WS_CNT);
    void*     out  = d_out;

    sniff_kernel<<<1, 64, 0, stream>>>(uWih, flag);
    spk_prep_kernel<<<1, 64, 0, stream>>>(spk_agents, EV, CNT);

    // utterance encoder (MFMA; dtype-dispatched on flag)
    vocab_utt_kernel<<<250, 512, 0, stream>>>(emb_u, uWih, ubih, UQ, USC, flag);
    rec_utt_kernel<<<200, 512, 0, stream>>>(ctx_tok, UQ, USC, uWhh, ubhh, H_u, flag);

    // agent tables H2D (bf16 bits) — after rec_utt so it may alias the dead UQ tail
    hipMemcpyAsync(tbl, get_host_tables(), 835584 * sizeof(uint16_t),
                   hipMemcpyHostToDevice, stream);

    // fused gate kernel: respgi (400 blk) ∥ gi_ctx (200 blk)
    gates2_kernel<<<600, 512, 0, stream>>>(rsp_tok, emb_r, rWih, rbih, RG,
                                           H_u, tbl, spk_agents, cWih, cbih, GIc, flag);

    // fused recurrence: ctx_rec (4 blk) ∥ rec_resp (8 blk)
    rec2_kernel<<<12, 512, 0, stream>>>(GIc, cWhh, cbhh, CO,
                                        RG, rWhh, rbhh, out, flag);

    // speaker pipeline: gates GEMM, then chain-decomposed GRU (Kmax ~ 6-8 steps)
    gi_spk_kernel<<<200, 512, 0, stream>>>(CO, sWih, sbih, GIs, flag);
    spk_chain_kernel<<<204, 512, 0, stream>>>(GIs, sWhh, sbhh, EV, CNT, out, flag);
}